// Round 16
// baseline (392.315 us; speedup 1.0000x reference)
//
#include <hip/hip_runtime.h>

// PINN jets via MFMA, round 16: r15 verbatim (passed, 110.8 us, absmax at
// bf16 floor) with ONE change: __launch_bounds__(128, 6) to raise resident
// waves/SIMD (r15: VGPR=64, LDS=0, occupancy only 37% with min-waves hint 4).
// VGPR cap at 6 waves/EU ~= 85 >= the 64 the allocator already uses -> no
// spill risk; pure scheduling change, numerics identical.
//
// Structure: transposed network (zero cross-lane), fast K=32 MFMA, slot-
// permuted K, precision-tiered (jet0 3-term / jet1 2-term / jet2,3 1-term;
// head a0 3/a1 2/a3 1; final F 1-term, Mdt 2-term), zero-LDS (u0 in regs,
// direct float4 stores), 128-thread/2-wave blocks.

typedef float f32x4 __attribute__((ext_vector_type(4)));
typedef short s16x8 __attribute__((ext_vector_type(8)));
typedef unsigned int u32x4 __attribute__((ext_vector_type(4)));

// ws layout (ushort units):
constexpr int WH_LO = 16384, WO_HI = 32768, WO_LO = 39936;
constexpr int MD_HI = 47104, MD_LO = 61440;

__device__ __forceinline__ unsigned short f2b(float v) {
    unsigned int u = __builtin_bit_cast(unsigned int, v);
    unsigned int r = (u + 0x7FFFu + ((u >> 16) & 1u)) >> 16;   // RNE
    return (unsigned short)r;
}
__device__ __forceinline__ float b2f(unsigned short h) {
    return __builtin_bit_cast(float, (unsigned int)h << 16);
}
__device__ __forceinline__ unsigned int cvtpk(float lo, float hi) {
    unsigned int r;
    asm("v_cvt_pk_bf16_f32 %0, %1, %2" : "=v"(r) : "v"(lo), "v"(hi));
    return r;   // low16 = bf16(lo), high16 = bf16(hi)
}
__device__ __forceinline__ void cvt2(float v0, float v1,
                                     unsigned int& hp, unsigned int& lp) {
    hp = cvtpk(v0, v1);
    float r0 = v0 - __builtin_bit_cast(float, hp << 16);
    float r1 = v1 - __builtin_bit_cast(float, hp & 0xFFFF0000u);
    lp = cvtpk(r0, r1);
}
__device__ __forceinline__ s16x8 asfrag(u32x4 u) {
    return __builtin_bit_cast(s16x8, u);
}
__device__ __forceinline__ f32x4 mm(s16x8 a, s16x8 b, f32x4 c) {
    return __builtin_amdgcn_mfma_f32_16x16x32_bf16(a, b, c, 0, 0, 0);
}
__device__ __forceinline__ float ftanh(float z) {
    float e = __expf(2.0f * z);
    float r = __builtin_amdgcn_rcpf(e + 1.0f);
    return fmaf(-2.0f, r, 1.0f);
}

__global__ __launch_bounds__(256) void pinn_prep(
    const float* __restrict__ alpha, const float* __restrict__ beta,
    const float* __restrict__ dtp,
    const float* __restrict__ W2, const float* __restrict__ W3,
    const float* __restrict__ W4, const float* __restrict__ W5,
    const float* __restrict__ Wout, unsigned short* __restrict__ wsu)
{
    int i = blockIdx.x * 256 + threadIdx.x;
    float v; int hi_off, lo_off;
    if (i < 16384) {                                   // hidden W^T A-frags
        int l = i >> 12, r = i & 4095;
        int t = r >> 9, jrt = t >> 1, krt = t & 1;
        int lane = (r >> 3) & 63, e = r & 7;
        int gg = lane >> 4;
        int j = 16 * jrt + (lane & 15);
        int n = 32 * krt + 16 * (e >> 2) + 4 * gg + (e & 3);
        const float* W = (l == 0) ? W2 : (l == 1) ? W3 : (l == 2) ? W4 : W5;
        v = (n < 50 && j < 50) ? W[n * 50 + j] : 0.0f;
        hi_off = i; lo_off = i + WH_LO;
    } else if (i < 23552) {                            // Wout^T A-frags
        int r = i - 16384;
        int t = r >> 9, jrt = t >> 1, krt = t & 1;
        int lane = (r >> 3) & 63, e = r & 7;
        int gg = lane >> 4;
        int j = 16 * jrt + (lane & 15);
        int n = 32 * krt + 16 * (e >> 2) + 4 * gg + (e & 3);
        v = (n < 50 && j < 100) ? Wout[n * 100 + j] : 0.0f;
        hi_off = WO_HI + r; lo_off = WO_LO + r;
    } else if (i < 37888) {                            // Mdt^T A-frags
        int r = i - 23552;
        int t = r >> 9, jrt = t >> 2, kt = t & 3;
        int lane = (r >> 3) & 63, e = r & 7;
        int gg = lane >> 4;
        int j = 16 * jrt + (lane & 15);
        int k = 32 * kt + 16 * (e >> 2) + 4 * gg + (e & 3);
        v = (j < 100 && k < 100) ? dtp[0] * (beta[k] - alpha[j * 100 + k]) : 0.0f;
        hi_off = MD_HI + r; lo_off = MD_LO + r;
    } else return;
    unsigned short h = f2b(v);
    wsu[hi_off] = h;
    wsu[lo_off] = f2b(v - b2f(h));
}

// One hidden layer, precision-tiered, split accumulator chains.
__device__ __forceinline__ void hidden_layer(
    const unsigned short* __restrict__ wsu, int Lb,
    const float* __restrict__ bias, int ln, int gg,
    const u32x4 (&gh)[2][4], const u32x4 (&gl0)[2],
    u32x4 (&nh)[2][4], u32x4 (&nl0)[2])
{
#pragma unroll
    for (int kd = 0; kd < 2; ++kd) {
#pragma unroll
        for (int ct = 0; ct < 4; ++ct) nh[kd][ct] = (u32x4){0u, 0u, 0u, 0u};
        nl0[kd] = (u32x4){0u, 0u, 0u, 0u};
    }
#pragma unroll
    for (int jrt = 0; jrt < 4; ++jrt) {
        f32x4 accA[4];
        f32x4 accB0a = {0.f, 0.f, 0.f, 0.f}, accB0b = {0.f, 0.f, 0.f, 0.f};
        f32x4 accB1  = {0.f, 0.f, 0.f, 0.f};
#pragma unroll
        for (int ct = 0; ct < 4; ++ct) accA[ct] = (f32x4){0.f, 0.f, 0.f, 0.f};
#pragma unroll
        for (int krt = 0; krt < 2; ++krt) {
            s16x8 wh = *(const s16x8*)(wsu + Lb + (jrt * 2 + krt) * 512 + ln * 8);
            s16x8 wl = *(const s16x8*)(wsu + WH_LO + Lb + (jrt * 2 + krt) * 512 + ln * 8);
            s16x8 b0h = asfrag(gh[krt][0]);
            s16x8 b0l = asfrag(gl0[krt]);
            s16x8 b1h = asfrag(gh[krt][1]);
            accA[0] = mm(wh, b0h, accA[0]);                 // jet0: 3-term
            accB0a  = mm(wh, b0l, accB0a);
            accB0b  = mm(wl, b0h, accB0b);
            accA[1] = mm(wh, b1h, accA[1]);                 // jet1: 2-term
            accB1   = mm(wl, b1h, accB1);
            accA[2] = mm(wh, asfrag(gh[krt][2]), accA[2]);  // jet2: 1-term
            accA[3] = mm(wh, asfrag(gh[krt][3]), accA[3]);  // jet3: 1-term
        }
        float bv[4];
        if (jrt < 3) {
            float4 b4 = *(const float4*)(bias + 16 * jrt + 4 * gg);
            bv[0] = b4.x; bv[1] = b4.y; bv[2] = b4.z; bv[3] = b4.w;
        } else {
#pragma unroll
            for (int r = 0; r < 4; ++r) {
                int j = 48 + 4 * gg + r;
                bv[r] = (j < 50) ? bias[j] : 0.0f;
            }
        }
        float m[4][4];
#pragma unroll
        for (int r = 0; r < 4; ++r) {
            float z0 = (accA[0][r] + accB0a[r]) + (accB0b[r] + bv[r]);
            float z1 = accA[1][r] + accB1[r];
            float z2 = accA[2][r];
            float z3 = accA[3][r];
            float t  = ftanh(z0);
            float sd = fmaf(-t, t, 1.0f);
            float c2 = -2.0f * t * sd;
            float c3 = -2.0f * sd * fmaf(3.0f, sd, -2.0f);
            float z1sq = z1 * z1;
            m[0][r] = t;
            m[1][r] = sd * z1;
            m[2][r] = fmaf(c2, z1sq, sd * z2);
            m[3][r] = fmaf(c3, z1sq * z1, fmaf(3.0f * c2, z1 * z2, sd * z3));
        }
        const int kd = jrt >> 1, p = jrt & 1;
        {   // jet0: hi + lo
            unsigned int hp0, lp0, hp1, lp1;
            cvt2(m[0][0], m[0][1], hp0, lp0);
            cvt2(m[0][2], m[0][3], hp1, lp1);
            nh[kd][0][2 * p]     = hp0;
            nh[kd][0][2 * p + 1] = hp1;
            nl0[kd][2 * p]       = lp0;
            nl0[kd][2 * p + 1]   = lp1;
        }
#pragma unroll
        for (int ct = 1; ct < 4; ++ct) {                    // jets 1-3: hi only
            nh[kd][ct][2 * p]     = cvtpk(m[ct][0], m[ct][1]);
            nh[kd][ct][2 * p + 1] = cvtpk(m[ct][2], m[ct][3]);
        }
    }
}

__global__ __launch_bounds__(128, 6) void pinn_main(
    const float* __restrict__ X, int N,
    const float* __restrict__ W1, const float* __restrict__ b1,
    const float* __restrict__ b2, const float* __restrict__ b3,
    const float* __restrict__ b4, const float* __restrict__ b5,
    const float* __restrict__ bout,
    const float* __restrict__ l1p, const float* __restrict__ l2p,
    const unsigned short* __restrict__ wsu,
    float* __restrict__ out)
{
    const int tid = threadIdx.x;
    const int wv = tid >> 6, ln = tid & 63;
    const int cc = ln & 15, gg = ln >> 4;
    const int n0 = blockIdx.x * 32 + wv * 16;

    u32x4 gAh[2][4], gAl0[2], gBh[2][4], gBl0[2];
#pragma unroll
    for (int krt = 0; krt < 2; ++krt) {
#pragma unroll
        for (int ct = 0; ct < 4; ++ct) gAh[krt][ct] = (u32x4){0u, 0u, 0u, 0u};
        gAl0[krt] = (u32x4){0u, 0u, 0u, 0u};
    }

    // ---- layer 1: width 1 -> 50, jets (x,1,0,0), in-lane packing ----
    float x = (n0 + cc < N) ? X[n0 + cc] : 0.0f;
#pragma unroll
    for (int krt = 0; krt < 2; ++krt)
#pragma unroll
        for (int jf = 0; jf < 2; ++jf) {
            float m[4][4];
#pragma unroll
            for (int q = 0; q < 4; ++q) {
                int n = 32 * krt + 16 * jf + 4 * gg + q;
                float w = (n < 50) ? W1[n] : 0.0f;
                float b = (n < 50) ? b1[n] : 0.0f;
                float z0 = fmaf(x, w, b);
                float t  = ftanh(z0);
                float sd = fmaf(-t, t, 1.0f);
                float c2 = -2.0f * t * sd;
                float c3 = -2.0f * sd * fmaf(3.0f, sd, -2.0f);
                float w2 = w * w;
                m[0][q] = t; m[1][q] = sd * w; m[2][q] = c2 * w2; m[3][q] = c3 * w2 * w;
            }
            {
                unsigned int hp0, lp0, hp1, lp1;
                cvt2(m[0][0], m[0][1], hp0, lp0);
                cvt2(m[0][2], m[0][3], hp1, lp1);
                gAh[krt][0][2 * jf]     = hp0;
                gAh[krt][0][2 * jf + 1] = hp1;
                gAl0[krt][2 * jf]       = lp0;
                gAl0[krt][2 * jf + 1]   = lp1;
            }
#pragma unroll
            for (int ct = 1; ct < 4; ++ct) {
                gAh[krt][ct][2 * jf]     = cvtpk(m[ct][0], m[ct][1]);
                gAh[krt][ct][2 * jf + 1] = cvtpk(m[ct][2], m[ct][3]);
            }
        }

    // ---- layers 2..5 (A->B->A->B->A) ----
#pragma unroll 1
    for (int L = 0; L < 2; ++L) {
        hidden_layer(wsu, (2 * L) * 4096,     (L == 0) ? b2 : b4, ln, gg,
                     gAh, gAl0, gBh, gBl0);
        hidden_layer(wsu, (2 * L + 1) * 4096, (L == 0) ? b3 : b5, ln, gg,
                     gBh, gBl0, gAh, gAl0);
    }

    // ---- head: a0 3-term (split chains), a1 2-term, a3 1-term; u0 in regs ----
    const float l1v = l1p[0], l2v = l2p[0];
    float u0s[7][4];
    u32x4 fhU[4];
#pragma unroll
    for (int kt = 0; kt < 4; ++kt) fhU[kt] = (u32x4){0u, 0u, 0u, 0u};
#pragma unroll
    for (int jrt = 0; jrt < 7; ++jrt) {
        f32x4 a0A = {0.f, 0.f, 0.f, 0.f}, a0B = {0.f, 0.f, 0.f, 0.f};
        f32x4 a0C = {0.f, 0.f, 0.f, 0.f};
        f32x4 a1A = {0.f, 0.f, 0.f, 0.f}, a1B = {0.f, 0.f, 0.f, 0.f};
        f32x4 a3A = {0.f, 0.f, 0.f, 0.f};
#pragma unroll
        for (int krt = 0; krt < 2; ++krt) {
            s16x8 wh = *(const s16x8*)(wsu + WO_HI + (jrt * 2 + krt) * 512 + ln * 8);
            s16x8 wl = *(const s16x8*)(wsu + WO_LO + (jrt * 2 + krt) * 512 + ln * 8);
            s16x8 b0h = asfrag(gAh[krt][0]);
            s16x8 b0l = asfrag(gAl0[krt]);
            s16x8 b1h = asfrag(gAh[krt][1]);
            a0A = mm(wh, b0h, a0A);
            a0B = mm(wh, b0l, a0B);
            a0C = mm(wl, b0h, a0C);
            a1A = mm(wh, b1h, a1A);
            a1B = mm(wl, b1h, a1B);
            a3A = mm(wh, asfrag(gAh[krt][3]), a3A);
        }
        float bo[4];
        if (jrt < 6) {
            float4 b4 = *(const float4*)(bout + 16 * jrt + 4 * gg);
            bo[0] = b4.x; bo[1] = b4.y; bo[2] = b4.z; bo[3] = b4.w;
        } else {
#pragma unroll
            for (int r = 0; r < 4; ++r) {
                int j = 96 + 4 * gg + r;
                bo[r] = (j < 100) ? bout[j] : 0.0f;
            }
        }
        float fv[4];
#pragma unroll
        for (int r = 0; r < 4; ++r) {
            float u0 = (a0A[r] + a0B[r]) + (a0C[r] + bo[r]);
            u0s[jrt][r] = u0;
            fv[r] = -(l1v * u0) * (a1A[r] + a1B[r]) - l2v * a3A[r];
        }
        const int kt = jrt >> 1, p = jrt & 1;
        fhU[kt][2 * p]     = cvtpk(fv[0], fv[1]);
        fhU[kt][2 * p + 1] = cvtpk(fv[2], fv[3]);
    }

    // ---- final: out = u0 + Mdt^T @ F^T; direct float4 store per jrt ----
    const bool act = (n0 + cc) < N;
    float* orow = out + (size_t)(n0 + cc) * 100;
#pragma unroll
    for (int jrt = 0; jrt < 7; ++jrt) {
        f32x4 accA = {0.f, 0.f, 0.f, 0.f}, accB = {0.f, 0.f, 0.f, 0.f};
        f32x4 accC = {0.f, 0.f, 0.f, 0.f}, accD = {0.f, 0.f, 0.f, 0.f};
#pragma unroll
        for (int kt = 0; kt < 4; ++kt) {
            s16x8 mh = *(const s16x8*)(wsu + MD_HI + (jrt * 4 + kt) * 512 + ln * 8);
            s16x8 ml = *(const s16x8*)(wsu + MD_LO + (jrt * 4 + kt) * 512 + ln * 8);
            s16x8 fb = asfrag(fhU[kt]);
            if (kt & 1) { accC = mm(mh, fb, accC); accD = mm(ml, fb, accD); }
            else        { accA = mm(mh, fb, accA); accB = mm(ml, fb, accB); }
        }
        if (act && (jrt < 6 || gg == 0)) {
            float4 v = make_float4(
                u0s[jrt][0] + (accA[0] + accB[0]) + (accC[0] + accD[0]),
                u0s[jrt][1] + (accA[1] + accB[1]) + (accC[1] + accD[1]),
                u0s[jrt][2] + (accA[2] + accB[2]) + (accC[2] + accD[2]),
                u0s[jrt][3] + (accA[3] + accB[3]) + (accC[3] + accD[3]));
            *(float4*)(orow + 16 * jrt + 4 * gg) = v;
        }
    }
}

extern "C" void kernel_launch(void* const* d_in, const int* in_sizes, int n_in,
                              void* d_out, int out_size, void* d_ws, size_t ws_size,
                              hipStream_t stream)
{
    const float* X     = (const float*)d_in[0];
    const float* dt    = (const float*)d_in[1];
    const float* alpha = (const float*)d_in[2];
    const float* beta  = (const float*)d_in[3];
    const float* W1    = (const float*)d_in[4];
    const float* b1    = (const float*)d_in[5];
    const float* W2    = (const float*)d_in[6];
    const float* b2    = (const float*)d_in[7];
    const float* W3    = (const float*)d_in[8];
    const float* b3    = (const float*)d_in[9];
    const float* W4    = (const float*)d_in[10];
    const float* b4    = (const float*)d_in[11];
    const float* W5    = (const float*)d_in[12];
    const float* b5    = (const float*)d_in[13];
    const float* Wout  = (const float*)d_in[14];
    const float* bout  = (const float*)d_in[15];
    const float* l1    = (const float*)d_in[16];
    const float* l2    = (const float*)d_in[17];

    unsigned short* wsu = (unsigned short*)d_ws;
    int N = in_sizes[0];

    pinn_prep<<<148, 256, 0, stream>>>(alpha, beta, dt, W2, W3, W4, W5, Wout, wsu);

    int grid = (N + 31) / 32;
    pinn_main<<<grid, 128, 0, stream>>>(X, N, W1, b1, b2, b3, b4, b5,
                                        bout, l1, l2, wsu, (float*)d_out);
}

// Round 17
// 108.503 us; speedup vs baseline: 3.6157x; 3.6157x over previous
//
#include <hip/hip_runtime.h>

// PINN jets via MFMA, round 17: r15 kernel (passed, 110.8 us, absmax at bf16
// floor) with __launch_bounds__(128, 3). Round-16 lesson: on gfx950 the
// min-waves arg sets the VGPR cap ~= 256/min_waves ((128,4)->64, (128,6)->40
// -> spill disaster). (128,3) -> cap ~85 >= the ~64 demanded: gives the
// allocator headroom to drop rematerialization/v_mov traffic (suspected
// cause of r15's 74us VALU-busy vs ~30us of actual math). Occupancy floor
// 3 waves/EU = what r15 actually achieved, so no downside.
//
// Structure: transposed network (zero cross-lane), fast K=32 MFMA, slot-
// permuted K, precision-tiered (jet0 3-term / jet1 2-term / jet2,3 1-term;
// head a0 3/a1 2/a3 1; final F 1-term, Mdt 2-term), zero-LDS (u0 in regs,
// direct float4 stores), 128-thread/2-wave blocks.

typedef float f32x4 __attribute__((ext_vector_type(4)));
typedef short s16x8 __attribute__((ext_vector_type(8)));
typedef unsigned int u32x4 __attribute__((ext_vector_type(4)));

// ws layout (ushort units):
constexpr int WH_LO = 16384, WO_HI = 32768, WO_LO = 39936;
constexpr int MD_HI = 47104, MD_LO = 61440;

__device__ __forceinline__ unsigned short f2b(float v) {
    unsigned int u = __builtin_bit_cast(unsigned int, v);
    unsigned int r = (u + 0x7FFFu + ((u >> 16) & 1u)) >> 16;   // RNE
    return (unsigned short)r;
}
__device__ __forceinline__ float b2f(unsigned short h) {
    return __builtin_bit_cast(float, (unsigned int)h << 16);
}
__device__ __forceinline__ unsigned int cvtpk(float lo, float hi) {
    unsigned int r;
    asm("v_cvt_pk_bf16_f32 %0, %1, %2" : "=v"(r) : "v"(lo), "v"(hi));
    return r;   // low16 = bf16(lo), high16 = bf16(hi)
}
__device__ __forceinline__ void cvt2(float v0, float v1,
                                     unsigned int& hp, unsigned int& lp) {
    hp = cvtpk(v0, v1);
    float r0 = v0 - __builtin_bit_cast(float, hp << 16);
    float r1 = v1 - __builtin_bit_cast(float, hp & 0xFFFF0000u);
    lp = cvtpk(r0, r1);
}
__device__ __forceinline__ s16x8 asfrag(u32x4 u) {
    return __builtin_bit_cast(s16x8, u);
}
__device__ __forceinline__ f32x4 mm(s16x8 a, s16x8 b, f32x4 c) {
    return __builtin_amdgcn_mfma_f32_16x16x32_bf16(a, b, c, 0, 0, 0);
}
__device__ __forceinline__ float ftanh(float z) {
    float e = __expf(2.0f * z);
    float r = __builtin_amdgcn_rcpf(e + 1.0f);
    return fmaf(-2.0f, r, 1.0f);
}

__global__ __launch_bounds__(256) void pinn_prep(
    const float* __restrict__ alpha, const float* __restrict__ beta,
    const float* __restrict__ dtp,
    const float* __restrict__ W2, const float* __restrict__ W3,
    const float* __restrict__ W4, const float* __restrict__ W5,
    const float* __restrict__ Wout, unsigned short* __restrict__ wsu)
{
    int i = blockIdx.x * 256 + threadIdx.x;
    float v; int hi_off, lo_off;
    if (i < 16384) {                                   // hidden W^T A-frags
        int l = i >> 12, r = i & 4095;
        int t = r >> 9, jrt = t >> 1, krt = t & 1;
        int lane = (r >> 3) & 63, e = r & 7;
        int gg = lane >> 4;
        int j = 16 * jrt + (lane & 15);
        int n = 32 * krt + 16 * (e >> 2) + 4 * gg + (e & 3);
        const float* W = (l == 0) ? W2 : (l == 1) ? W3 : (l == 2) ? W4 : W5;
        v = (n < 50 && j < 50) ? W[n * 50 + j] : 0.0f;
        hi_off = i; lo_off = i + WH_LO;
    } else if (i < 23552) {                            // Wout^T A-frags
        int r = i - 16384;
        int t = r >> 9, jrt = t >> 1, krt = t & 1;
        int lane = (r >> 3) & 63, e = r & 7;
        int gg = lane >> 4;
        int j = 16 * jrt + (lane & 15);
        int n = 32 * krt + 16 * (e >> 2) + 4 * gg + (e & 3);
        v = (n < 50 && j < 100) ? Wout[n * 100 + j] : 0.0f;
        hi_off = WO_HI + r; lo_off = WO_LO + r;
    } else if (i < 37888) {                            // Mdt^T A-frags
        int r = i - 23552;
        int t = r >> 9, jrt = t >> 2, kt = t & 3;
        int lane = (r >> 3) & 63, e = r & 7;
        int gg = lane >> 4;
        int j = 16 * jrt + (lane & 15);
        int k = 32 * kt + 16 * (e >> 2) + 4 * gg + (e & 3);
        v = (j < 100 && k < 100) ? dtp[0] * (beta[k] - alpha[j * 100 + k]) : 0.0f;
        hi_off = MD_HI + r; lo_off = MD_LO + r;
    } else return;
    unsigned short h = f2b(v);
    wsu[hi_off] = h;
    wsu[lo_off] = f2b(v - b2f(h));
}

// One hidden layer, precision-tiered, split accumulator chains.
__device__ __forceinline__ void hidden_layer(
    const unsigned short* __restrict__ wsu, int Lb,
    const float* __restrict__ bias, int ln, int gg,
    const u32x4 (&gh)[2][4], const u32x4 (&gl0)[2],
    u32x4 (&nh)[2][4], u32x4 (&nl0)[2])
{
#pragma unroll
    for (int kd = 0; kd < 2; ++kd) {
#pragma unroll
        for (int ct = 0; ct < 4; ++ct) nh[kd][ct] = (u32x4){0u, 0u, 0u, 0u};
        nl0[kd] = (u32x4){0u, 0u, 0u, 0u};
    }
#pragma unroll
    for (int jrt = 0; jrt < 4; ++jrt) {
        f32x4 accA[4];
        f32x4 accB0a = {0.f, 0.f, 0.f, 0.f}, accB0b = {0.f, 0.f, 0.f, 0.f};
        f32x4 accB1  = {0.f, 0.f, 0.f, 0.f};
#pragma unroll
        for (int ct = 0; ct < 4; ++ct) accA[ct] = (f32x4){0.f, 0.f, 0.f, 0.f};
#pragma unroll
        for (int krt = 0; krt < 2; ++krt) {
            s16x8 wh = *(const s16x8*)(wsu + Lb + (jrt * 2 + krt) * 512 + ln * 8);
            s16x8 wl = *(const s16x8*)(wsu + WH_LO + Lb + (jrt * 2 + krt) * 512 + ln * 8);
            s16x8 b0h = asfrag(gh[krt][0]);
            s16x8 b0l = asfrag(gl0[krt]);
            s16x8 b1h = asfrag(gh[krt][1]);
            accA[0] = mm(wh, b0h, accA[0]);                 // jet0: 3-term
            accB0a  = mm(wh, b0l, accB0a);
            accB0b  = mm(wl, b0h, accB0b);
            accA[1] = mm(wh, b1h, accA[1]);                 // jet1: 2-term
            accB1   = mm(wl, b1h, accB1);
            accA[2] = mm(wh, asfrag(gh[krt][2]), accA[2]);  // jet2: 1-term
            accA[3] = mm(wh, asfrag(gh[krt][3]), accA[3]);  // jet3: 1-term
        }
        float bv[4];
        if (jrt < 3) {
            float4 b4 = *(const float4*)(bias + 16 * jrt + 4 * gg);
            bv[0] = b4.x; bv[1] = b4.y; bv[2] = b4.z; bv[3] = b4.w;
        } else {
#pragma unroll
            for (int r = 0; r < 4; ++r) {
                int j = 48 + 4 * gg + r;
                bv[r] = (j < 50) ? bias[j] : 0.0f;
            }
        }
        float m[4][4];
#pragma unroll
        for (int r = 0; r < 4; ++r) {
            float z0 = (accA[0][r] + accB0a[r]) + (accB0b[r] + bv[r]);
            float z1 = accA[1][r] + accB1[r];
            float z2 = accA[2][r];
            float z3 = accA[3][r];
            float t  = ftanh(z0);
            float sd = fmaf(-t, t, 1.0f);
            float c2 = -2.0f * t * sd;
            float c3 = -2.0f * sd * fmaf(3.0f, sd, -2.0f);
            float z1sq = z1 * z1;
            m[0][r] = t;
            m[1][r] = sd * z1;
            m[2][r] = fmaf(c2, z1sq, sd * z2);
            m[3][r] = fmaf(c3, z1sq * z1, fmaf(3.0f * c2, z1 * z2, sd * z3));
        }
        const int kd = jrt >> 1, p = jrt & 1;
        {   // jet0: hi + lo
            unsigned int hp0, lp0, hp1, lp1;
            cvt2(m[0][0], m[0][1], hp0, lp0);
            cvt2(m[0][2], m[0][3], hp1, lp1);
            nh[kd][0][2 * p]     = hp0;
            nh[kd][0][2 * p + 1] = hp1;
            nl0[kd][2 * p]       = lp0;
            nl0[kd][2 * p + 1]   = lp1;
        }
#pragma unroll
        for (int ct = 1; ct < 4; ++ct) {                    // jets 1-3: hi only
            nh[kd][ct][2 * p]     = cvtpk(m[ct][0], m[ct][1]);
            nh[kd][ct][2 * p + 1] = cvtpk(m[ct][2], m[ct][3]);
        }
    }
}

__global__ __launch_bounds__(128, 3) void pinn_main(
    const float* __restrict__ X, int N,
    const float* __restrict__ W1, const float* __restrict__ b1,
    const float* __restrict__ b2, const float* __restrict__ b3,
    const float* __restrict__ b4, const float* __restrict__ b5,
    const float* __restrict__ bout,
    const float* __restrict__ l1p, const float* __restrict__ l2p,
    const unsigned short* __restrict__ wsu,
    float* __restrict__ out)
{
    const int tid = threadIdx.x;
    const int wv = tid >> 6, ln = tid & 63;
    const int cc = ln & 15, gg = ln >> 4;
    const int n0 = blockIdx.x * 32 + wv * 16;

    u32x4 gAh[2][4], gAl0[2], gBh[2][4], gBl0[2];
#pragma unroll
    for (int krt = 0; krt < 2; ++krt) {
#pragma unroll
        for (int ct = 0; ct < 4; ++ct) gAh[krt][ct] = (u32x4){0u, 0u, 0u, 0u};
        gAl0[krt] = (u32x4){0u, 0u, 0u, 0u};
    }

    // ---- layer 1: width 1 -> 50, jets (x,1,0,0), in-lane packing ----
    float x = (n0 + cc < N) ? X[n0 + cc] : 0.0f;
#pragma unroll
    for (int krt = 0; krt < 2; ++krt)
#pragma unroll
        for (int jf = 0; jf < 2; ++jf) {
            float m[4][4];
#pragma unroll
            for (int q = 0; q < 4; ++q) {
                int n = 32 * krt + 16 * jf + 4 * gg + q;
                float w = (n < 50) ? W1[n] : 0.0f;
                float b = (n < 50) ? b1[n] : 0.0f;
                float z0 = fmaf(x, w, b);
                float t  = ftanh(z0);
                float sd = fmaf(-t, t, 1.0f);
                float c2 = -2.0f * t * sd;
                float c3 = -2.0f * sd * fmaf(3.0f, sd, -2.0f);
                float w2 = w * w;
                m[0][q] = t; m[1][q] = sd * w; m[2][q] = c2 * w2; m[3][q] = c3 * w2 * w;
            }
            {
                unsigned int hp0, lp0, hp1, lp1;
                cvt2(m[0][0], m[0][1], hp0, lp0);
                cvt2(m[0][2], m[0][3], hp1, lp1);
                gAh[krt][0][2 * jf]     = hp0;
                gAh[krt][0][2 * jf + 1] = hp1;
                gAl0[krt][2 * jf]       = lp0;
                gAl0[krt][2 * jf + 1]   = lp1;
            }
#pragma unroll
            for (int ct = 1; ct < 4; ++ct) {
                gAh[krt][ct][2 * jf]     = cvtpk(m[ct][0], m[ct][1]);
                gAh[krt][ct][2 * jf + 1] = cvtpk(m[ct][2], m[ct][3]);
            }
        }

    // ---- layers 2..5 (A->B->A->B->A) ----
#pragma unroll 1
    for (int L = 0; L < 2; ++L) {
        hidden_layer(wsu, (2 * L) * 4096,     (L == 0) ? b2 : b4, ln, gg,
                     gAh, gAl0, gBh, gBl0);
        hidden_layer(wsu, (2 * L + 1) * 4096, (L == 0) ? b3 : b5, ln, gg,
                     gBh, gBl0, gAh, gAl0);
    }

    // ---- head: a0 3-term (split chains), a1 2-term, a3 1-term; u0 in regs ----
    const float l1v = l1p[0], l2v = l2p[0];
    float u0s[7][4];
    u32x4 fhU[4];
#pragma unroll
    for (int kt = 0; kt < 4; ++kt) fhU[kt] = (u32x4){0u, 0u, 0u, 0u};
#pragma unroll
    for (int jrt = 0; jrt < 7; ++jrt) {
        f32x4 a0A = {0.f, 0.f, 0.f, 0.f}, a0B = {0.f, 0.f, 0.f, 0.f};
        f32x4 a0C = {0.f, 0.f, 0.f, 0.f};
        f32x4 a1A = {0.f, 0.f, 0.f, 0.f}, a1B = {0.f, 0.f, 0.f, 0.f};
        f32x4 a3A = {0.f, 0.f, 0.f, 0.f};
#pragma unroll
        for (int krt = 0; krt < 2; ++krt) {
            s16x8 wh = *(const s16x8*)(wsu + WO_HI + (jrt * 2 + krt) * 512 + ln * 8);
            s16x8 wl = *(const s16x8*)(wsu + WO_LO + (jrt * 2 + krt) * 512 + ln * 8);
            s16x8 b0h = asfrag(gAh[krt][0]);
            s16x8 b0l = asfrag(gAl0[krt]);
            s16x8 b1h = asfrag(gAh[krt][1]);
            a0A = mm(wh, b0h, a0A);
            a0B = mm(wh, b0l, a0B);
            a0C = mm(wl, b0h, a0C);
            a1A = mm(wh, b1h, a1A);
            a1B = mm(wl, b1h, a1B);
            a3A = mm(wh, asfrag(gAh[krt][3]), a3A);
        }
        float bo[4];
        if (jrt < 6) {
            float4 b4 = *(const float4*)(bout + 16 * jrt + 4 * gg);
            bo[0] = b4.x; bo[1] = b4.y; bo[2] = b4.z; bo[3] = b4.w;
        } else {
#pragma unroll
            for (int r = 0; r < 4; ++r) {
                int j = 96 + 4 * gg + r;
                bo[r] = (j < 100) ? bout[j] : 0.0f;
            }
        }
        float fv[4];
#pragma unroll
        for (int r = 0; r < 4; ++r) {
            float u0 = (a0A[r] + a0B[r]) + (a0C[r] + bo[r]);
            u0s[jrt][r] = u0;
            fv[r] = -(l1v * u0) * (a1A[r] + a1B[r]) - l2v * a3A[r];
        }
        const int kt = jrt >> 1, p = jrt & 1;
        fhU[kt][2 * p]     = cvtpk(fv[0], fv[1]);
        fhU[kt][2 * p + 1] = cvtpk(fv[2], fv[3]);
    }

    // ---- final: out = u0 + Mdt^T @ F^T; direct float4 store per jrt ----
    const bool act = (n0 + cc) < N;
    float* orow = out + (size_t)(n0 + cc) * 100;
#pragma unroll
    for (int jrt = 0; jrt < 7; ++jrt) {
        f32x4 accA = {0.f, 0.f, 0.f, 0.f}, accB = {0.f, 0.f, 0.f, 0.f};
        f32x4 accC = {0.f, 0.f, 0.f, 0.f}, accD = {0.f, 0.f, 0.f, 0.f};
#pragma unroll
        for (int kt = 0; kt < 4; ++kt) {
            s16x8 mh = *(const s16x8*)(wsu + MD_HI + (jrt * 4 + kt) * 512 + ln * 8);
            s16x8 ml = *(const s16x8*)(wsu + MD_LO + (jrt * 4 + kt) * 512 + ln * 8);
            s16x8 fb = asfrag(fhU[kt]);
            if (kt & 1) { accC = mm(mh, fb, accC); accD = mm(ml, fb, accD); }
            else        { accA = mm(mh, fb, accA); accB = mm(ml, fb, accB); }
        }
        if (act && (jrt < 6 || gg == 0)) {
            float4 v = make_float4(
                u0s[jrt][0] + (accA[0] + accB[0]) + (accC[0] + accD[0]),
                u0s[jrt][1] + (accA[1] + accB[1]) + (accC[1] + accD[1]),
                u0s[jrt][2] + (accA[2] + accB[2]) + (accC[2] + accD[2]),
                u0s[jrt][3] + (accA[3] + accB[3]) + (accC[3] + accD[3]));
            *(float4*)(orow + 16 * jrt + 4 * gg) = v;
        }
    }
}

extern "C" void kernel_launch(void* const* d_in, const int* in_sizes, int n_in,
                              void* d_out, int out_size, void* d_ws, size_t ws_size,
                              hipStream_t stream)
{
    const float* X     = (const float*)d_in[0];
    const float* dt    = (const float*)d_in[1];
    const float* alpha = (const float*)d_in[2];
    const float* beta  = (const float*)d_in[3];
    const float* W1    = (const float*)d_in[4];
    const float* b1    = (const float*)d_in[5];
    const float* W2    = (const float*)d_in[6];
    const float* b2    = (const float*)d_in[7];
    const float* W3    = (const float*)d_in[8];
    const float* b3    = (const float*)d_in[9];
    const float* W4    = (const float*)d_in[10];
    const float* b4    = (const float*)d_in[11];
    const float* W5    = (const float*)d_in[12];
    const float* b5    = (const float*)d_in[13];
    const float* Wout  = (const float*)d_in[14];
    const float* bout  = (const float*)d_in[15];
    const float* l1    = (const float*)d_in[16];
    const float* l2    = (const float*)d_in[17];

    unsigned short* wsu = (unsigned short*)d_ws;
    int N = in_sizes[0];

    pinn_prep<<<148, 256, 0, stream>>>(alpha, beta, dt, W2, W3, W4, W5, Wout, wsu);

    int grid = (N + 31) / 32;
    pinn_main<<<grid, 128, 0, stream>>>(X, N, W1, b1, b2, b3, b4, b5,
                                        bout, l1, l2, wsu, (float*)d_out);
}